// Round 1
// baseline (1033.107 us; speedup 1.0000x reference)
//
#include <hip/hip_runtime.h>
#include <math.h>

// Problem constants (from reference)
//  B=256, S2=32768, HID=512, HEADS=1024
// Pipeline:
//  c1  = tanh(input @ W_c1^T + b_c1)          [256,512]
//  cx  = sigmoid(c1 @ W_c2^T)[:,0]            [256]
//  x1  = kwta(input @ W1^T + b1, int(cx*1024))[256,1024]
//  x2  = kwta(x1 @ W2^T + b2,  int(cx*512))  [256,512]
//  x3  = kwta(x2 @ W3^T + b3,  int(cx*1024)) [256,1024]
//  out = x3 @ W4^T                            [256,1024]

#define BM 64
#define BN 64
#define BK 16
#define PAD 4  // keeps 4-float micro-rows 16B aligned for ds_read_b128

// C[M,N] = A[M,K] @ W[N,K]^T  (+bias, +act) or partial write P[z][M][N]
// act: 0 = none, 1 = tanh
__global__ __launch_bounds__(256) void gemm_nt(
    const float* __restrict__ A, const float* __restrict__ W,
    float* __restrict__ P, const float* __restrict__ bias,
    int M, int N, int K, int kChunk, int act, int finalWrite) {
  __shared__ float As[BK][BM + PAD];
  __shared__ float Ws[BK][BN + PAD];
  const int tid = threadIdx.x;
  const int n0 = blockIdx.x * BN;
  const int m0 = blockIdx.y * BM;
  const int z = blockIdx.z;
  const int kStart = z * kChunk;
  const int kEnd = kStart + kChunk;  // all K divisible by kChunk here
  const int tx = tid & 15;
  const int ty = tid >> 4;
  const int kcol = tid & 15;   // k within tile
  const int rrow = tid >> 4;   // row group base

  float acc[4][4];
#pragma unroll
  for (int i = 0; i < 4; ++i)
#pragma unroll
    for (int j = 0; j < 4; ++j) acc[i][j] = 0.f;

  for (int kk = kStart; kk < kEnd; kk += BK) {
#pragma unroll
    for (int l = 0; l < 4; ++l) {
      const int mr = rrow + 16 * l;
      As[kcol][mr] = A[(size_t)(m0 + mr) * K + kk + kcol];
      Ws[kcol][mr] = W[(size_t)(n0 + mr) * K + kk + kcol];
    }
    __syncthreads();
#pragma unroll
    for (int k = 0; k < BK; ++k) {
      float a[4], w[4];
#pragma unroll
      for (int i = 0; i < 4; ++i) a[i] = As[k][4 * ty + i];
#pragma unroll
      for (int j = 0; j < 4; ++j) w[j] = Ws[k][4 * tx + j];
#pragma unroll
      for (int i = 0; i < 4; ++i)
#pragma unroll
        for (int j = 0; j < 4; ++j) acc[i][j] += a[i] * w[j];
    }
    __syncthreads();
  }

  if (finalWrite) {
#pragma unroll
    for (int i = 0; i < 4; ++i) {
      const int m = m0 + 4 * ty + i;
#pragma unroll
      for (int j = 0; j < 4; ++j) {
        const int n = n0 + 4 * tx + j;
        float v = acc[i][j];
        if (bias) v += bias[n];
        if (act == 1) v = tanhf(v);
        P[(size_t)m * N + n] = v;
      }
    }
  } else {
    const size_t MN = (size_t)M * N;
    const size_t base = (size_t)z * MN;
#pragma unroll
    for (int i = 0; i < 4; ++i) {
      const int m = m0 + 4 * ty + i;
#pragma unroll
      for (int j = 0; j < 4; ++j) {
        const int n = n0 + 4 * tx + j;
        P[base + (size_t)m * N + n] = acc[i][j];
      }
    }
  }
}

// Deterministic split-K reduction + bias + activation
__global__ __launch_bounds__(256) void reduce_epilogue(
    const float* __restrict__ P, float* __restrict__ C,
    const float* __restrict__ bias, int MN, int N, int S, int act) {
  const int idx = blockIdx.x * blockDim.x + threadIdx.x;
  if (idx >= MN) return;
  float s = 0.f;
  for (int i = 0; i < S; ++i) s += P[(size_t)i * MN + idx];
  if (bias) s += bias[idx & (N - 1)];
  if (act == 1) s = tanhf(s);
  C[idx] = s;
}

// cx[row] = sigmoid(dot(C1[row,:], Wc2[:]))  — one wave per row
__global__ __launch_bounds__(256) void cx_kernel(
    const float* __restrict__ C1, const float* __restrict__ Wc2,
    float* __restrict__ cx, int H) {
  const int wave = threadIdx.x >> 6;
  const int lane = threadIdx.x & 63;
  const int row = blockIdx.x * 4 + wave;
  float s = 0.f;
  for (int h = lane; h < H; h += 64) s += C1[(size_t)row * H + h] * Wc2[h];
#pragma unroll
  for (int off = 32; off > 0; off >>= 1) s += __shfl_down(s, off, 64);
  if (lane == 0) cx[row] = 1.f / (1.f + expf(-s));
}

// Per-row top-k winner-take-all with exact stable-argsort tie semantics.
// rank(j) = #{i : x[i] > x[j]} + #{i < j : x[i] == x[j]}; keep rank < k.
// One block per row, n threads, LDS-broadcast O(n) rank count per thread.
__global__ void kwta_kernel(float* __restrict__ x,
                            const float* __restrict__ cx, int n) {
  extern __shared__ float sdata[];
  const int row = blockIdx.x;
  const int j = threadIdx.x;
  float* xr = x + (size_t)row * n;
  const float v = xr[j];
  sdata[j] = v;
  __syncthreads();
  const int k = (int)(cx[row] * (float)n);  // trunc toward zero, matches .astype(int32)
  int rank = 0;
  for (int i = 0; i < n; ++i) {
    const float si = sdata[i];  // same address across lanes -> LDS broadcast
    rank += (si > v || (si == v && i < j)) ? 1 : 0;
  }
  xr[j] = (rank < k) ? v : 0.f;
}

extern "C" void kernel_launch(void* const* d_in, const int* in_sizes, int n_in,
                              void* d_out, int out_size, void* d_ws, size_t ws_size,
                              hipStream_t stream) {
  const float* input = (const float*)d_in[0];   // [256, 32768]
  const float* W_c1  = (const float*)d_in[1];   // [512, 32768]
  const float* b_c1  = (const float*)d_in[2];   // [512]
  const float* W_c2  = (const float*)d_in[3];   // [1, 512]
  const float* W1    = (const float*)d_in[4];   // [1024, 32768]
  const float* b1    = (const float*)d_in[5];   // [1024]
  const float* W2    = (const float*)d_in[6];   // [512, 1024]
  const float* b2    = (const float*)d_in[7];   // [512]
  const float* W3    = (const float*)d_in[8];   // [1024, 512]
  const float* b3    = (const float*)d_in[9];   // [1024]
  const float* W4    = (const float*)d_in[10];  // [1024, 1024]
  float* out = (float*)d_out;                   // [256, 1024]

  const int B = 256, S2 = 32768, HID = 512, HEADS = 1024;

  float* wsf = (float*)d_ws;
  float* cx   = wsf;                       // 256 floats
  float* buf1 = wsf + 256;                 // 131072 floats: c1, then x2
  float* buf2 = wsf + 256 + 131072;        // 262144 floats: x1, then x3
  const size_t persist = 256 + 131072 + 262144;
  const size_t pNeedFloats = 8ull * 256 * 1024;  // S=8 partials for biggest GEMM
  const int S = (ws_size >= (persist + pNeedFloats) * sizeof(float)) ? 8 : 1;
  float* P = wsf + persist;

  // ---- gemm1: c1 = tanh(input @ W_c1^T + b_c1), M=256,N=512,K=32768
  if (S > 1) {
    dim3 g(HID / BN, B / BM, S);
    gemm_nt<<<g, 256, 0, stream>>>(input, W_c1, P, nullptr, B, HID, S2, S2 / S, 0, 0);
    reduce_epilogue<<<(B * HID + 255) / 256, 256, 0, stream>>>(P, buf1, b_c1, B * HID, HID, S, 1);
  } else {
    dim3 g(HID / BN, B / BM, 1);
    gemm_nt<<<g, 256, 0, stream>>>(input, W_c1, buf1, b_c1, B, HID, S2, S2, 1, 1);
  }

  // ---- cx = sigmoid(c1 @ W_c2^T)
  cx_kernel<<<B / 4, 256, 0, stream>>>(buf1, W_c2, cx, HID);

  // ---- gemm2: x1 = input @ W1^T + b1, M=256,N=1024,K=32768 -> buf2
  if (S > 1) {
    dim3 g(HEADS / BN, B / BM, S);
    gemm_nt<<<g, 256, 0, stream>>>(input, W1, P, nullptr, B, HEADS, S2, S2 / S, 0, 0);
    reduce_epilogue<<<(B * HEADS + 255) / 256, 256, 0, stream>>>(P, buf2, b1, B * HEADS, HEADS, S, 0);
  } else {
    dim3 g(HEADS / BN, B / BM, 1);
    gemm_nt<<<g, 256, 0, stream>>>(input, W1, buf2, b1, B, HEADS, S2, S2, 0, 1);
  }

  // ---- kwta(x1, int(cx*1024))
  kwta_kernel<<<B, 1024, 1024 * sizeof(float), stream>>>(buf2, cx, 1024);

  // ---- gemm3: x2 = x1 @ W2^T + b2, M=256,N=512,K=1024 -> buf1
  {
    dim3 g(HID / BN, B / BM, 1);
    gemm_nt<<<g, 256, 0, stream>>>(buf2, W2, buf1, b2, B, HID, 2 * HID, 2 * HID, 0, 1);
  }

  // ---- kwta(x2, int(cx*512))
  kwta_kernel<<<B, 512, 512 * sizeof(float), stream>>>(buf1, cx, 512);

  // ---- gemm4: x3 = x2 @ W3^T + b3, M=256,N=1024,K=512 -> buf2
  {
    dim3 g(HEADS / BN, B / BM, 1);
    gemm_nt<<<g, 256, 0, stream>>>(buf1, W3, buf2, b3, B, HEADS, HID, HID, 0, 1);
  }

  // ---- kwta(x3, int(cx*1024))
  kwta_kernel<<<B, 1024, 1024 * sizeof(float), stream>>>(buf2, cx, 1024);

  // ---- gemm5: out = x3 @ W4^T, M=256,N=1024,K=1024
  {
    dim3 g(HEADS / BN, B / BM, 1);
    gemm_nt<<<g, 256, 0, stream>>>(buf2, W4, out, nullptr, B, HEADS, HEADS, HEADS, 0, 1);
  }
}

// Round 2
// 605.779 us; speedup vs baseline: 1.7054x; 1.7054x over previous
//
#include <hip/hip_runtime.h>
#include <math.h>

// B=256, S2=32768, HID=512, HEADS=1024
// Pipeline:
//  c1  = tanh(input @ W_c1^T + b_c1)          [256,512]
//  cx  = sigmoid(c1 @ W_c2^T)[:,0]            [256]
//  x1  = kwta(input @ W1^T + b1, int(cx*1024))[256,1024]
//  x2  = kwta(x1 @ W2^T + b2,  int(cx*512))   [256,512]
//  x3  = kwta(x2 @ W3^T + b3,  int(cx*1024))  [256,1024]
//  out = x3 @ W4^T                            [256,1024]
//
// Big GEMMs (K=32768) fused into ONE split-bf16 3-term MFMA kernel over
// concatenated N=512+1024=1536.  Error of dropped lo*lo term ~2^-18 rel per
// product -> ~3e-6 absolute on dots (std 0.003), same order as fp32 noise.

typedef __attribute__((ext_vector_type(8))) short bf16x8;
typedef __attribute__((ext_vector_type(4))) float f32x4;

// ---------------------------------------------------------------------------
// Fused big GEMM: P[z] += A[256,32768] @ concat(W_c1,W1)[1536,32768]^T (chunk z)
// BM=128, BN=64, BK=32.  4 waves; wave w: m-half=(w&1) (4 m-tiles), n-half=(w>>1)
// (2 n-tiles) of 16x16x32 MFMA tiles. 3 MFMA per tile (hi*hi, hi*lo, lo*hi).
// LDS row stride 40 bf16 = 80 B (16B-aligned b128 reads, 2-way banks = free).
// ---------------------------------------------------------------------------
__global__ __launch_bounds__(256) void big_gemm(
    const float* __restrict__ A, const float* __restrict__ Wc1,
    const float* __restrict__ W1, float* __restrict__ P, int stepsPerZ) {
  __shared__ short sA[2][128 * 40];  // [hi/lo][row*40 + k]
  __shared__ short sW[2][64 * 40];

  const int tid = threadIdx.x;
  const int n0 = blockIdx.x * 64;   // 0..1472
  const int m0 = blockIdx.y * 128;  // 0 or 128
  const int z = blockIdx.z;
  const float* Wp = (n0 < 512) ? (Wc1 + (size_t)n0 * 32768)
                               : (W1 + (size_t)(n0 - 512) * 32768);

  const int lane = tid & 63;
  const int wv = tid >> 6;
  const int q = lane >> 4;     // quad
  const int l16 = lane & 15;
  const int mhalf = wv & 1;    // which 64-row half of the 128 M tile
  const int nhalf = wv >> 1;   // which 32-col half of the 64 N tile

  const int sr = tid >> 3;        // staging row 0..31
  const int sc = (tid & 7) * 4;   // staging col (floats)

  f32x4 acc[4][2];
#pragma unroll
  for (int i = 0; i < 4; ++i)
#pragma unroll
    for (int j = 0; j < 2; ++j) acc[i][j] = (f32x4){0.f, 0.f, 0.f, 0.f};

  int kk = z * stepsPerZ * 32;
  for (int s = 0; s < stepsPerZ; ++s, kk += 32) {
    // ---- stage A (128x32) and W (64x32), splitting fp32 -> bf16 hi + lo
#pragma unroll
    for (int p = 0; p < 4; ++p) {
      const int row = sr + p * 32;
      const float4 v = *(const float4*)(A + (size_t)(m0 + row) * 32768 + kk + sc);
      short4 h, l;
      const float* vf = (const float*)&v;
      short* hp = (short*)&h;
      short* lp = (short*)&l;
#pragma unroll
      for (int e = 0; e < 4; ++e) {
        const unsigned u = __float_as_uint(vf[e]);
        hp[e] = (short)(unsigned short)(u >> 16);
        const float r = vf[e] - __uint_as_float(u & 0xffff0000u);
        lp[e] = (short)(unsigned short)(__float_as_uint(r) >> 16);
      }
      *(short4*)(&sA[0][row * 40 + sc]) = h;
      *(short4*)(&sA[1][row * 40 + sc]) = l;
    }
#pragma unroll
    for (int p = 0; p < 2; ++p) {
      const int row = sr + p * 32;
      const float4 v = *(const float4*)(Wp + (size_t)row * 32768 + kk + sc);
      short4 h, l;
      const float* vf = (const float*)&v;
      short* hp = (short*)&h;
      short* lp = (short*)&l;
#pragma unroll
      for (int e = 0; e < 4; ++e) {
        const unsigned u = __float_as_uint(vf[e]);
        hp[e] = (short)(unsigned short)(u >> 16);
        const float r = vf[e] - __uint_as_float(u & 0xffff0000u);
        lp[e] = (short)(unsigned short)(__float_as_uint(r) >> 16);
      }
      *(short4*)(&sW[0][row * 40 + sc]) = h;
      *(short4*)(&sW[1][row * 40 + sc]) = l;
    }
    __syncthreads();

    // ---- fragment loads (b128) + MFMA
    bf16x8 af[4][2], wf[2][2];
#pragma unroll
    for (int i = 0; i < 4; ++i) {
      const int row = mhalf * 64 + i * 16 + l16;
      af[i][0] = *(const bf16x8*)(&sA[0][row * 40 + q * 8]);
      af[i][1] = *(const bf16x8*)(&sA[1][row * 40 + q * 8]);
    }
#pragma unroll
    for (int j = 0; j < 2; ++j) {
      const int row = nhalf * 32 + j * 16 + l16;
      wf[j][0] = *(const bf16x8*)(&sW[0][row * 40 + q * 8]);
      wf[j][1] = *(const bf16x8*)(&sW[1][row * 40 + q * 8]);
    }
#pragma unroll
    for (int i = 0; i < 4; ++i)
#pragma unroll
      for (int j = 0; j < 2; ++j) {
        acc[i][j] = __builtin_amdgcn_mfma_f32_16x16x32_bf16(af[i][0], wf[j][0], acc[i][j], 0, 0, 0);
        acc[i][j] = __builtin_amdgcn_mfma_f32_16x16x32_bf16(af[i][0], wf[j][1], acc[i][j], 0, 0, 0);
        acc[i][j] = __builtin_amdgcn_mfma_f32_16x16x32_bf16(af[i][1], wf[j][0], acc[i][j], 0, 0, 0);
      }
    __syncthreads();
  }

  // ---- write partials: C/D layout col=lane&15 (n), row=quad*4+reg (m)
#pragma unroll
  for (int i = 0; i < 4; ++i)
#pragma unroll
    for (int j = 0; j < 2; ++j)
#pragma unroll
      for (int r = 0; r < 4; ++r) {
        const int m = m0 + mhalf * 64 + i * 16 + q * 4 + r;
        const int n = n0 + nhalf * 32 + j * 16 + l16;
        P[((size_t)z * 256 + m) * 1536 + n] = acc[i][j][r];
      }
}

// Reduce split-K partials of the fused big GEMM; split into c1 (tanh) and x1.
__global__ __launch_bounds__(256) void reduce_big(
    const float* __restrict__ P, float* __restrict__ c1, float* __restrict__ x1,
    const float* __restrict__ b_c1, const float* __restrict__ b1, int S) {
  const int idx = blockIdx.x * 256 + threadIdx.x;  // over 256*1536
  const int m = idx / 1536;
  const int n = idx - m * 1536;
  float s = 0.f;
  for (int zz = 0; zz < S; ++zz) s += P[(size_t)zz * 393216 + idx];
  if (n < 512) {
    c1[m * 512 + n] = tanhf(s + b_c1[n]);
  } else {
    x1[m * 1024 + (n - 512)] = s + b1[n - 512];
  }
}

// ---------------------------------------------------------------------------
// fp32 tiled GEMM for the small layers: C = A[M,K] @ W[N,K]^T + bias
// ---------------------------------------------------------------------------
#define BM 64
#define BN 64
#define BK 16
#define PAD 4

__global__ __launch_bounds__(256) void gemm_nt(
    const float* __restrict__ A, const float* __restrict__ W,
    float* __restrict__ C, const float* __restrict__ bias,
    int M, int N, int K) {
  __shared__ float As[BK][BM + PAD];
  __shared__ float Ws[BK][BN + PAD];
  const int tid = threadIdx.x;
  const int n0 = blockIdx.x * BN;
  const int m0 = blockIdx.y * BM;
  const int tx = tid & 15;
  const int ty = tid >> 4;
  const int kcol = tid & 15;
  const int rrow = tid >> 4;

  float acc[4][4];
#pragma unroll
  for (int i = 0; i < 4; ++i)
#pragma unroll
    for (int j = 0; j < 4; ++j) acc[i][j] = 0.f;

  for (int kk = 0; kk < K; kk += BK) {
#pragma unroll
    for (int l = 0; l < 4; ++l) {
      const int mr = rrow + 16 * l;
      As[kcol][mr] = A[(size_t)(m0 + mr) * K + kk + kcol];
      Ws[kcol][mr] = W[(size_t)(n0 + mr) * K + kk + kcol];
    }
    __syncthreads();
#pragma unroll
    for (int k = 0; k < BK; ++k) {
      float a[4], w[4];
#pragma unroll
      for (int i = 0; i < 4; ++i) a[i] = As[k][4 * ty + i];
#pragma unroll
      for (int j = 0; j < 4; ++j) w[j] = Ws[k][4 * tx + j];
#pragma unroll
      for (int i = 0; i < 4; ++i)
#pragma unroll
        for (int j = 0; j < 4; ++j) acc[i][j] += a[i] * w[j];
    }
    __syncthreads();
  }

#pragma unroll
  for (int i = 0; i < 4; ++i) {
    const int m = m0 + 4 * ty + i;
#pragma unroll
    for (int j = 0; j < 4; ++j) {
      const int n = n0 + 4 * tx + j;
      float v = acc[i][j];
      if (bias) v += bias[n];
      C[(size_t)m * N + n] = v;
    }
  }
}

// cx[row] = sigmoid(dot(C1[row,:], Wc2[:]))  — one wave per row
__global__ __launch_bounds__(256) void cx_kernel(
    const float* __restrict__ C1, const float* __restrict__ Wc2,
    float* __restrict__ cx, int H) {
  const int wave = threadIdx.x >> 6;
  const int lane = threadIdx.x & 63;
  const int row = blockIdx.x * 4 + wave;
  float s = 0.f;
  for (int h = lane; h < H; h += 64) s += C1[(size_t)row * H + h] * Wc2[h];
#pragma unroll
  for (int off = 32; off > 0; off >>= 1) s += __shfl_down(s, off, 64);
  if (lane == 0) cx[row] = 1.f / (1.f + expf(-s));
}

// Per-row top-k WTA, exact stable-argsort tie semantics.
__global__ void kwta_kernel(float* __restrict__ x,
                            const float* __restrict__ cx, int n) {
  extern __shared__ float sdata[];
  const int row = blockIdx.x;
  const int j = threadIdx.x;
  float* xr = x + (size_t)row * n;
  const float v = xr[j];
  sdata[j] = v;
  __syncthreads();
  const int k = (int)(cx[row] * (float)n);
  int rank = 0;
  for (int i = 0; i < n; ++i) {
    const float si = sdata[i];
    rank += (si > v || (si == v && i < j)) ? 1 : 0;
  }
  xr[j] = (rank < k) ? v : 0.f;
}

extern "C" void kernel_launch(void* const* d_in, const int* in_sizes, int n_in,
                              void* d_out, int out_size, void* d_ws, size_t ws_size,
                              hipStream_t stream) {
  const float* input = (const float*)d_in[0];
  const float* W_c1  = (const float*)d_in[1];
  const float* b_c1  = (const float*)d_in[2];
  const float* W_c2  = (const float*)d_in[3];
  const float* W1    = (const float*)d_in[4];
  const float* b1    = (const float*)d_in[5];
  const float* W2    = (const float*)d_in[6];
  const float* b2    = (const float*)d_in[7];
  const float* W3    = (const float*)d_in[8];
  const float* b3    = (const float*)d_in[9];
  const float* W4    = (const float*)d_in[10];
  float* out = (float*)d_out;

  const int B = 256, HID = 512, HEADS = 1024;

  float* wsf = (float*)d_ws;
  float* cx   = wsf;                       // 256
  float* buf1 = wsf + 256;                 // 131072: c1, then x2
  float* buf2 = wsf + 256 + 131072;        // 262144: x1, then x3
  const size_t persist = 256 + 131072 + 262144;  // floats
  float* P = wsf + persist;

  // Split-K factor: S in {16,8,4,2,1} dividing 1024 K-steps, sized to ws.
  int S = 16;
  while (S > 1 &&
         (persist + (size_t)S * 393216ull) * sizeof(float) > ws_size)
    S >>= 1;
  const int stepsPerZ = 1024 / S;  // K-steps of 32 per z-chunk

  // ---- fused big GEMM (c1-preact | x1-preact), split-K partials
  {
    dim3 g(1536 / 64, B / 128, S);
    big_gemm<<<g, 256, 0, stream>>>(input, W_c1, W1, P, stepsPerZ);
    reduce_big<<<(B * 1536) / 256, 256, 0, stream>>>(P, buf1, buf2, b_c1, b1, S);
  }

  // ---- cx = sigmoid(c1 @ W_c2^T)
  cx_kernel<<<B / 4, 256, 0, stream>>>(buf1, W_c2, cx, HID);

  // ---- kwta(x1, int(cx*1024))
  kwta_kernel<<<B, 1024, 1024 * sizeof(float), stream>>>(buf2, cx, 1024);

  // ---- x2 = x1 @ W2^T + b2
  {
    dim3 g(HID / BN, B / BM);
    gemm_nt<<<g, 256, 0, stream>>>(buf2, W2, buf1, b2, B, HID, 2 * HID);
  }

  // ---- kwta(x2, int(cx*512))
  kwta_kernel<<<B, 512, 512 * sizeof(float), stream>>>(buf1, cx, 512);

  // ---- x3 = x2 @ W3^T + b3
  {
    dim3 g(HEADS / BN, B / BM);
    gemm_nt<<<g, 256, 0, stream>>>(buf1, W3, buf2, b3, B, HEADS, HID);
  }

  // ---- kwta(x3, int(cx*1024))
  kwta_kernel<<<B, 1024, 1024 * sizeof(float), stream>>>(buf2, cx, 1024);

  // ---- out = x3 @ W4^T
  {
    dim3 g(HEADS / BN, B / BM);
    gemm_nt<<<g, 256, 0, stream>>>(buf2, W4, out, nullptr, B, HEADS, HEADS);
  }
}

// Round 3
// 514.482 us; speedup vs baseline: 2.0081x; 1.1775x over previous
//
#include <hip/hip_runtime.h>
#include <math.h>

// B=256, S2=32768, HID=512, HEADS=1024
// c1 = tanh(in@W_c1^T+b_c1); cx = sigmoid(c1@W_c2^T); x1 = kwta(in@W1^T+b1, cx*1024)
// x2 = kwta(x1@W2^T+b2, cx*512); x3 = kwta(x2@W3^T+b3, cx*1024); out = x3@W4^T
//
// All GEMMs: split-bf16 3-term MFMA (hi*hi + hi*lo + lo*hi); dropped lo*lo is
// ~2^-18 relative. Big GEMM fuses W_c1|W1 (N=1536, K=32768), 32x32x16 MFMA.
// Small GEMMs use R2-verified 16x16x32 path with pre-split weights; kwta
// kernels fuse split-K reduce + bias + top-k + hi/lo emit.

typedef __attribute__((ext_vector_type(8))) short bf16x8;
typedef __attribute__((ext_vector_type(4))) float f32x4;
typedef __attribute__((ext_vector_type(16))) float f32x16;

// Pack two fp32 into bf16-hi pair and bf16-lo (residual) pair via v_perm.
__device__ __forceinline__ void split2(float f0, float f1, unsigned& hi, unsigned& lo) {
  unsigned u0 = __float_as_uint(f0), u1 = __float_as_uint(f1);
  hi = __builtin_amdgcn_perm(u1, u0, 0x07060302u);  // (u1_hi16<<16)|u0_hi16
  float r0 = f0 - __uint_as_float(u0 & 0xffff0000u);
  float r1 = f1 - __uint_as_float(u1 & 0xffff0000u);
  lo = __builtin_amdgcn_perm(__float_as_uint(r1), __float_as_uint(r0), 0x07060302u);
}

// ---------------------------------------------------------------------------
// Pre-split W2 (512x1024), W3 (1024x512), W4 (1024x1024) into bf16 hi/lo.
// Total 2,097,152 elements; 8 per thread -> 1024 blocks.
// ---------------------------------------------------------------------------
__global__ __launch_bounds__(256) void presplit_w(
    const float* __restrict__ W2, const float* __restrict__ W3,
    const float* __restrict__ W4, short* __restrict__ W2h, short* __restrict__ W2l,
    short* __restrict__ W3h, short* __restrict__ W3l,
    short* __restrict__ W4h, short* __restrict__ W4l) {
  const int e = (blockIdx.x * 256 + threadIdx.x) * 8;
  const float* src; short *dh, *dl; int off;
  if (e < 524288) { src = W2; dh = W2h; dl = W2l; off = e; }
  else if (e < 1048576) { src = W3; dh = W3h; dl = W3l; off = e - 524288; }
  else { src = W4; dh = W4h; dl = W4l; off = e - 1048576; }
  const float4 a = *(const float4*)(src + off);
  const float4 b = *(const float4*)(src + off + 4);
  unsigned h0, l0, h1, l1, h2, l2, h3, l3;
  split2(a.x, a.y, h0, l0); split2(a.z, a.w, h1, l1);
  split2(b.x, b.y, h2, l2); split2(b.z, b.w, h3, l3);
  *(uint4*)(dh + off) = (uint4){h0, h1, h2, h3};
  *(uint4*)(dl + off) = (uint4){l0, l1, l2, l3};
}

// ---------------------------------------------------------------------------
// Big fused GEMM: P[z] = A[256,32768] @ concat(W_c1,W1)[1536,32768]^T chunk z.
// BM=128, BN=128, BK=32; 4 waves in 2x2; wave tile 64x64 = 2x2 of 32x32x16.
// On-the-fly hi/lo split (perm-packed). LDS stride 40 shorts (80 B).
// ---------------------------------------------------------------------------
__global__ __launch_bounds__(256, 3) void big_gemm2(
    const float* __restrict__ A, const float* __restrict__ Wc1,
    const float* __restrict__ W1, float* __restrict__ P, int stepsPerZ) {
  __shared__ short sAh[128 * 40], sAl[128 * 40], sWh[128 * 40], sWl[128 * 40];
  const int tid = threadIdx.x;
  const int n0 = blockIdx.x * 128;
  const int m0 = blockIdx.y * 128;
  const int z = blockIdx.z;
  const float* Wp = (n0 < 512) ? (Wc1 + (size_t)n0 * 32768)
                               : (W1 + (size_t)(n0 - 512) * 32768);
  const int lane = tid & 63, wv = tid >> 6;
  const int wm = wv & 1, wn = wv >> 1;
  const int l31 = lane & 31, khalf = lane >> 5;
  const int srow = tid >> 1, shalf = tid & 1;  // staging: 2 threads/row, 16 floats each

  f32x16 acc[2][2];
#pragma unroll
  for (int i = 0; i < 2; ++i)
#pragma unroll
    for (int j = 0; j < 2; ++j)
#pragma unroll
      for (int r = 0; r < 16; ++r) acc[i][j][r] = 0.f;

  const float* Ap = A + (size_t)(m0 + srow) * 32768 + shalf * 16;
  const float* Wq = Wp + (size_t)srow * 32768 + shalf * 16;
  short* dAh = &sAh[srow * 40 + shalf * 16];
  short* dAl = &sAl[srow * 40 + shalf * 16];
  short* dWh = &sWh[srow * 40 + shalf * 16];
  short* dWl = &sWl[srow * 40 + shalf * 16];

  int kk = z * stepsPerZ * 32;
  for (int s = 0; s < stepsPerZ; ++s, kk += 32) {
#pragma unroll
    for (int c = 0; c < 4; ++c) {
      const float4 v = *(const float4*)(Ap + kk + c * 4);
      unsigned h0, l0, h1, l1;
      split2(v.x, v.y, h0, l0); split2(v.z, v.w, h1, l1);
      *(uint2*)(dAh + c * 4) = (uint2){h0, h1};
      *(uint2*)(dAl + c * 4) = (uint2){l0, l1};
    }
#pragma unroll
    for (int c = 0; c < 4; ++c) {
      const float4 v = *(const float4*)(Wq + kk + c * 4);
      unsigned h0, l0, h1, l1;
      split2(v.x, v.y, h0, l0); split2(v.z, v.w, h1, l1);
      *(uint2*)(dWh + c * 4) = (uint2){h0, h1};
      *(uint2*)(dWl + c * 4) = (uint2){l0, l1};
    }
    __syncthreads();
#pragma unroll
    for (int ks = 0; ks < 2; ++ks) {
      bf16x8 ah[2], al[2], wh[2], wl[2];
#pragma unroll
      for (int i = 0; i < 2; ++i) {
        const int off = (wm * 64 + i * 32 + l31) * 40 + ks * 16 + khalf * 8;
        ah[i] = *(const bf16x8*)&sAh[off];
        al[i] = *(const bf16x8*)&sAl[off];
      }
#pragma unroll
      for (int j = 0; j < 2; ++j) {
        const int off = (wn * 64 + j * 32 + l31) * 40 + ks * 16 + khalf * 8;
        wh[j] = *(const bf16x8*)&sWh[off];
        wl[j] = *(const bf16x8*)&sWl[off];
      }
#pragma unroll
      for (int i = 0; i < 2; ++i)
#pragma unroll
        for (int j = 0; j < 2; ++j) {
          acc[i][j] = __builtin_amdgcn_mfma_f32_32x32x16_bf16(ah[i], wh[j], acc[i][j], 0, 0, 0);
          acc[i][j] = __builtin_amdgcn_mfma_f32_32x32x16_bf16(ah[i], wl[j], acc[i][j], 0, 0, 0);
          acc[i][j] = __builtin_amdgcn_mfma_f32_32x32x16_bf16(al[i], wh[j], acc[i][j], 0, 0, 0);
        }
    }
    __syncthreads();
  }
  // C/D layout (32x32): col = lane&31, row = (r&3) + 8*(r>>2) + 4*(lane>>5)
#pragma unroll
  for (int i = 0; i < 2; ++i)
#pragma unroll
    for (int j = 0; j < 2; ++j)
#pragma unroll
      for (int r = 0; r < 16; ++r) {
        const int m = m0 + wm * 64 + i * 32 + (r & 3) + 8 * (r >> 2) + 4 * khalf;
        const int n = n0 + wn * 64 + j * 32 + l31;
        P[((size_t)z * 256 + m) * 1536 + n] = acc[i][j][r];
      }
}

// ---------------------------------------------------------------------------
// cx = sigmoid(sum_n tanh(c1_preact)*Wc2). Fuses split-K reduce of c1 columns.
// One block (256 thr) per row; each thread 2 of the 512 columns.
// ---------------------------------------------------------------------------
__global__ __launch_bounds__(256) void cx_fused(
    const float* __restrict__ P, const float* __restrict__ b_c1,
    const float* __restrict__ Wc2, float* __restrict__ cx, int S) {
  const int r = blockIdx.x, t = threadIdx.x;
  __shared__ float red[4];
  float total = 0.f;
#pragma unroll
  for (int half = 0; half < 2; ++half) {
    const int c = t + half * 256;
    float s = 0.f;
    for (int z = 0; z < S; ++z) s += P[((size_t)z * 256 + r) * 1536 + c];
    total += tanhf(s + b_c1[c]) * Wc2[c];
  }
#pragma unroll
  for (int off = 32; off; off >>= 1) total += __shfl_down(total, off, 64);
  if ((t & 63) == 0) red[t >> 6] = total;
  __syncthreads();
  if (t == 0) {
    const float s = red[0] + red[1] + red[2] + red[3];
    cx[r] = 1.f / (1.f + expf(-s));
  }
}

// ---------------------------------------------------------------------------
// Fused: split-K reduce + bias -> kwta (exact stable-argsort ties) -> emit
// hi/lo bf16 for the next GEMM. One block per row, n threads.
// ---------------------------------------------------------------------------
__global__ void kwta_fused(
    const float* __restrict__ P, int ldP, int colOff, int S,
    const float* __restrict__ bias, const float* __restrict__ cx,
    short* __restrict__ xh, short* __restrict__ xl, int n) {
  extern __shared__ float sdata[];
  const int row = blockIdx.x, j = threadIdx.x;
  float v = 0.f;
  for (int z = 0; z < S; ++z) v += P[((size_t)z * 256 + row) * ldP + colOff + j];
  v += bias[j];
  sdata[j] = v;
  __syncthreads();
  const int k = (int)(cx[row] * (float)n);  // trunc, matches .astype(int32)
  int cnt = 0;
  const float4* s4 = (const float4*)sdata;
  for (int i4 = 0; i4 < (n >> 2); ++i4) {
    const float4 s = s4[i4];
    const int b = i4 << 2;
    cnt += (s.x > v || (s.x == v && b < j));
    cnt += (s.y > v || (s.y == v && b + 1 < j));
    cnt += (s.z > v || (s.z == v && b + 2 < j));
    cnt += (s.w > v || (s.w == v && b + 3 < j));
  }
  const float o = (cnt < k) ? v : 0.f;
  const unsigned u = __float_as_uint(o);
  xh[(size_t)row * n + j] = (short)(unsigned short)(u >> 16);
  const float rr = o - __uint_as_float(u & 0xffff0000u);
  xl[(size_t)row * n + j] = (short)(unsigned short)(__float_as_uint(rr) >> 16);
}

// ---------------------------------------------------------------------------
// Small GEMM, pre-split bf16 operands, 3-term 16x16x32 MFMA (R2-verified
// layout). Block 64x64, 4 waves (wave = 16 rows x 64 cols), split-K partials.
// ---------------------------------------------------------------------------
__global__ __launch_bounds__(256, 4) void gemm_sk(
    const short* __restrict__ Xh, const short* __restrict__ Xl,
    const short* __restrict__ Wh, const short* __restrict__ Wl,
    float* __restrict__ P, int N, int K, int stepsPerZ) {
  __shared__ short sXh[64 * 40], sXl[64 * 40], sWh[64 * 40], sWl[64 * 40];
  const int tid = threadIdx.x;
  const int n0 = blockIdx.x * 64, m0 = blockIdx.y * 64, z = blockIdx.z;
  const int lane = tid & 63, w = tid >> 6;
  const int l15 = lane & 15, q = lane >> 4;
  const int srow = tid >> 2, schunk = tid & 3;

  f32x4 acc[4];
#pragma unroll
  for (int j = 0; j < 4; ++j) acc[j] = (f32x4){0.f, 0.f, 0.f, 0.f};

  const short* pXh = Xh + (size_t)(m0 + srow) * K + schunk * 8;
  const short* pXl = Xl + (size_t)(m0 + srow) * K + schunk * 8;
  const short* pWh = Wh + (size_t)(n0 + srow) * K + schunk * 8;
  const short* pWl = Wl + (size_t)(n0 + srow) * K + schunk * 8;
  short* dXh = &sXh[srow * 40 + schunk * 8];
  short* dXl = &sXl[srow * 40 + schunk * 8];
  short* dWh = &sWh[srow * 40 + schunk * 8];
  short* dWl = &sWl[srow * 40 + schunk * 8];

  int kk = z * stepsPerZ * 32;
  for (int s = 0; s < stepsPerZ; ++s, kk += 32) {
    *(bf16x8*)dXh = *(const bf16x8*)(pXh + kk);
    *(bf16x8*)dXl = *(const bf16x8*)(pXl + kk);
    *(bf16x8*)dWh = *(const bf16x8*)(pWh + kk);
    *(bf16x8*)dWl = *(const bf16x8*)(pWl + kk);
    __syncthreads();
    const int aoff = (w * 16 + l15) * 40 + q * 8;
    const bf16x8 ah = *(const bf16x8*)&sXh[aoff];
    const bf16x8 al = *(const bf16x8*)&sXl[aoff];
#pragma unroll
    for (int j = 0; j < 4; ++j) {
      const int woff = (j * 16 + l15) * 40 + q * 8;
      const bf16x8 whf = *(const bf16x8*)&sWh[woff];
      const bf16x8 wlf = *(const bf16x8*)&sWl[woff];
      acc[j] = __builtin_amdgcn_mfma_f32_16x16x32_bf16(ah, whf, acc[j], 0, 0, 0);
      acc[j] = __builtin_amdgcn_mfma_f32_16x16x32_bf16(ah, wlf, acc[j], 0, 0, 0);
      acc[j] = __builtin_amdgcn_mfma_f32_16x16x32_bf16(al, whf, acc[j], 0, 0, 0);
    }
    __syncthreads();
  }
  // C/D (16x16): col = lane&15, row = (lane>>4)*4 + r
#pragma unroll
  for (int j = 0; j < 4; ++j)
#pragma unroll
    for (int r = 0; r < 4; ++r) {
      const int m = m0 + w * 16 + q * 4 + r;
      const int n = n0 + j * 16 + l15;
      P[((size_t)z * 256 + m) * N + n] = acc[j][r];
    }
}

__global__ __launch_bounds__(256) void reduce_out(
    const float* __restrict__ P, float* __restrict__ out, int S) {
  const int idx = blockIdx.x * 256 + threadIdx.x;
  float s = 0.f;
  for (int z = 0; z < S; ++z) s += P[(size_t)z * 262144 + idx];
  out[idx] = s;
}

extern "C" void kernel_launch(void* const* d_in, const int* in_sizes, int n_in,
                              void* d_out, int out_size, void* d_ws, size_t ws_size,
                              hipStream_t stream) {
  const float* input = (const float*)d_in[0];
  const float* W_c1  = (const float*)d_in[1];
  const float* b_c1  = (const float*)d_in[2];
  const float* W_c2  = (const float*)d_in[3];
  const float* W1    = (const float*)d_in[4];
  const float* b1    = (const float*)d_in[5];
  const float* W2    = (const float*)d_in[6];
  const float* b2    = (const float*)d_in[7];
  const float* W3    = (const float*)d_in[8];
  const float* b3    = (const float*)d_in[9];
  const float* W4    = (const float*)d_in[10];
  float* out = (float*)d_out;

  char* wsb = (char*)d_ws;
  size_t off = 0;
  auto alloc = [&](size_t bytes) {
    char* p = wsb + off;
    off += (bytes + 255) & ~(size_t)255;
    return p;
  };
  float* cx  = (float*)alloc(1024);
  short* x1h = (short*)alloc(524288);  short* x1l = (short*)alloc(524288);
  short* x2h = (short*)alloc(262144);  short* x2l = (short*)alloc(262144);
  short* x3h = (short*)alloc(524288);  short* x3l = (short*)alloc(524288);
  short* W2h = (short*)alloc(1048576); short* W2l = (short*)alloc(1048576);
  short* W3h = (short*)alloc(1048576); short* W3l = (short*)alloc(1048576);
  short* W4h = (short*)alloc(2097152); short* W4l = (short*)alloc(2097152);
  // Split-K partial buffer (big GEMM: S*256*1536 fp32; small GEMMs reuse <=4 MB)
  int S_big = 32;
  while (S_big > 8 && off + (size_t)S_big * 1572864ull > ws_size) S_big >>= 1;
  float* P = (float*)(wsb + off);
  const int stepsBig = 1024 / S_big;  // K-32 steps per z-chunk

  // 1. pre-split small weights
  presplit_w<<<1024, 256, 0, stream>>>(W2, W3, W4, W2h, W2l, W3h, W3l, W4h, W4l);
  // 2. big fused GEMM -> P
  {
    dim3 g(12, 2, S_big);
    big_gemm2<<<g, 256, 0, stream>>>(input, W_c1, W1, P, stepsBig);
  }
  // 3. cx (fuses c1 reduce + tanh + dot + sigmoid)
  cx_fused<<<256, 256, 0, stream>>>(P, b_c1, W_c2, cx, S_big);
  // 4. kwta x1 (reduce P cols 512..1536 + b1) -> x1h/x1l
  kwta_fused<<<256, 1024, 1024 * 4, stream>>>(P, 1536, 512, S_big, b1, cx, x1h, x1l, 1024);
  // 5. x2 = x1 @ W2^T : K=1024, N=512, S=8
  {
    dim3 g(8, 4, 8);
    gemm_sk<<<g, 256, 0, stream>>>(x1h, x1l, W2h, W2l, P, 512, 1024, 4);
  }
  // 6. kwta x2 (+b2) -> x2h/x2l
  kwta_fused<<<256, 512, 512 * 4, stream>>>(P, 512, 0, 8, b2, cx, x2h, x2l, 512);
  // 7. x3 = x2 @ W3^T : K=512, N=1024, S=4
  {
    dim3 g(16, 4, 4);
    gemm_sk<<<g, 256, 0, stream>>>(x2h, x2l, W3h, W3l, P, 1024, 512, 4);
  }
  // 8. kwta x3 (+b3) -> x3h/x3l
  kwta_fused<<<256, 1024, 1024 * 4, stream>>>(P, 1024, 0, 4, b3, cx, x3h, x3l, 1024);
  // 9. out = x3 @ W4^T : K=1024, N=1024, S=4
  {
    dim3 g(16, 4, 4);
    gemm_sk<<<g, 256, 0, stream>>>(x3h, x3l, W4h, W4l, P, 1024, 1024, 8);
  }
  // 10. final reduce
  reduce_out<<<1024, 256, 0, stream>>>(P, out, 4);
}